// Round 1
// baseline (194.621 us; speedup 1.0000x reference)
//
#include <hip/hip_runtime.h>
#include <hip/hip_bf16.h>
#include <math.h>

#define B_  4
#define S_  4096
#define D_  64
#define BR  64
#define BC  64
#define NQT (S_/BR)   // 64
#define LDK 72  // padded LDS stride (shorts): 144 B -> bank stride 4, spreads b128 reads
#define LDV 72
#define LDP 72

typedef __attribute__((ext_vector_type(8))) short bf16x8;   // 8 bf16 in 4 VGPRs
typedef __attribute__((ext_vector_type(4))) float f32x4;
typedef __attribute__((ext_vector_type(4))) short short4v;

static __device__ inline short f2bf(float f) {
    union { float f; unsigned u; } v; v.f = f;
    unsigned u = v.u;
    unsigned r = u + 0x7fff + ((u >> 16) & 1);   // round-to-nearest-even
    return (short)(r >> 16);
}

__global__ __launch_bounds__(256) void fa_fwd(const float* __restrict__ Q,
                                              const float* __restrict__ K,
                                              const float* __restrict__ V,
                                              float* __restrict__ O)
{
    const int qt   = (gridDim.x - 1) - blockIdx.x;  // longest jobs first
    const int b    = blockIdx.y;
    const int tid  = threadIdx.x;
    const int wave = tid >> 6;
    const int lane = tid & 63;
    const int lm   = lane & 15;   // 0..15
    const int lk   = lane >> 4;   // 0..3

    __shared__ short Ks[BC * LDK];   // K tile, [key][d], bf16
    __shared__ short Vt[D_ * LDV];   // V tile transposed, [d][key], bf16
    __shared__ short Ps[BR * LDP];   // P tile, [q][key], bf16 (per-wave 16-row regions)

    const float* Qb = Q + ((size_t)b * S_ + (size_t)qt * BR) * D_;
    const float* Kb = K + (size_t)b * S_ * D_;
    const float* Vb = V + (size_t)b * S_ * D_;

    // ---- Q fragments in registers, pre-scaled by 1/8 (exact in bf16) ----
    bf16x8 qA[2];
    {
        const float* qp = Qb + (wave * 16 + lm) * D_;
        #pragma unroll
        for (int h = 0; h < 2; ++h) {
            const float* p = qp + h * 32 + lk * 8;
            #pragma unroll
            for (int j = 0; j < 8; ++j) qA[h][j] = f2bf(p[j] * 0.125f);
        }
    }

    // online-softmax state: lane's 4 rows are (wave*16 + lk*4 + r)
    float m_i[4], l_i[4];
    f32x4 o_acc[4];   // [dt] d-col-tiles of 16; rows in regs (C-layout)
    #pragma unroll
    for (int r = 0; r < 4; ++r) { m_i[r] = -INFINITY; l_i[r] = 0.f; }
    #pragma unroll
    for (int dt = 0; dt < 4; ++dt) o_acc[dt] = (f32x4){0.f, 0.f, 0.f, 0.f};

    const int n_kt = qt + 1;   // causal: k-tiles 0..qt, last one masked
    for (int kt = 0; kt < n_kt; ++kt) {
        __syncthreads();   // prior iteration's LDS readers done
        // ---- stage K tile (bf16) and V^T tile (bf16) ----
        #pragma unroll
        for (int rr = 0; rr < 4; ++rr) {
            int i   = tid + rr * 256;     // float4 index 0..1023
            int row = i >> 4;             // key row 0..63
            int c4  = (i & 15) * 4;       // d col 0..60
            const size_t gbase = ((size_t)(kt * BC + row)) * D_ + c4;
            f32x4 kv = *(const f32x4*)(Kb + gbase);
            short4v ks;
            ks[0] = f2bf(kv[0]); ks[1] = f2bf(kv[1]);
            ks[2] = f2bf(kv[2]); ks[3] = f2bf(kv[3]);
            *(short4v*)&Ks[row * LDK + c4] = ks;
            f32x4 vv = *(const f32x4*)(Vb + gbase);
            Vt[(c4 + 0) * LDV + row] = f2bf(vv[0]);
            Vt[(c4 + 1) * LDV + row] = f2bf(vv[1]);
            Vt[(c4 + 2) * LDV + row] = f2bf(vv[2]);
            Vt[(c4 + 3) * LDV + row] = f2bf(vv[3]);
        }
        __syncthreads();

        // ---- S = Q K^T (scaled) for this wave's 16 rows ----
        f32x4 s[4];
        #pragma unroll
        for (int ct = 0; ct < 4; ++ct) {
            f32x4 acc = (f32x4){0.f, 0.f, 0.f, 0.f};
            #pragma unroll
            for (int h = 0; h < 2; ++h) {
                bf16x8 bF = *(const bf16x8*)&Ks[(ct * 16 + lm) * LDK + h * 32 + lk * 8];
                acc = __builtin_amdgcn_mfma_f32_16x16x32_bf16(qA[h], bF, acc, 0, 0, 0);
            }
            s[ct] = acc;
        }

        // ---- causal mask (diagonal tile only) ----
        if (kt == qt) {
            #pragma unroll
            for (int ct = 0; ct < 4; ++ct) {
                #pragma unroll
                for (int r = 0; r < 4; ++r) {
                    int qrow = wave * 16 + lk * 4 + r;
                    int kcol = ct * 16 + lm;
                    if (kcol > qrow) s[ct][r] = -INFINITY;
                }
            }
        }

        // ---- online softmax ----
        float alpha[4];
        #pragma unroll
        for (int r = 0; r < 4; ++r) {
            float mx = fmaxf(fmaxf(s[0][r], s[1][r]), fmaxf(s[2][r], s[3][r]));
            mx = fmaxf(mx, __shfl_xor(mx, 1));
            mx = fmaxf(mx, __shfl_xor(mx, 2));
            mx = fmaxf(mx, __shfl_xor(mx, 4));
            mx = fmaxf(mx, __shfl_xor(mx, 8));
            float mn = fmaxf(m_i[r], mx);
            alpha[r] = __expf(m_i[r] - mn);
            m_i[r] = mn;
        }
        float rsum[4] = {0.f, 0.f, 0.f, 0.f};
        #pragma unroll
        for (int ct = 0; ct < 4; ++ct) {
            #pragma unroll
            for (int r = 0; r < 4; ++r) {
                float p = __expf(s[ct][r] - m_i[r]);
                s[ct][r] = p;
                rsum[r] += p;
            }
        }
        #pragma unroll
        for (int r = 0; r < 4; ++r) {
            float rs = rsum[r];
            rs += __shfl_xor(rs, 1);
            rs += __shfl_xor(rs, 2);
            rs += __shfl_xor(rs, 4);
            rs += __shfl_xor(rs, 8);
            l_i[r] = l_i[r] * alpha[r] + rs;
        }
        // P -> LDS (per-wave region; no cross-wave readers, no barrier needed)
        #pragma unroll
        for (int ct = 0; ct < 4; ++ct) {
            #pragma unroll
            for (int r = 0; r < 4; ++r) {
                Ps[(wave * 16 + lk * 4 + r) * LDP + ct * 16 + lm] = f2bf(s[ct][r]);
            }
        }
        // rescale O
        #pragma unroll
        for (int dt = 0; dt < 4; ++dt) {
            #pragma unroll
            for (int r = 0; r < 4; ++r) o_acc[dt][r] *= alpha[r];
        }
        // ---- O += P V ----
        #pragma unroll
        for (int dt = 0; dt < 4; ++dt) {
            #pragma unroll
            for (int kh = 0; kh < 2; ++kh) {
                bf16x8 aF = *(const bf16x8*)&Ps[(wave * 16 + lm) * LDP + kh * 32 + lk * 8];
                bf16x8 bF = *(const bf16x8*)&Vt[(dt * 16 + lm) * LDV + kh * 32 + lk * 8];
                o_acc[dt] = __builtin_amdgcn_mfma_f32_16x16x32_bf16(aF, bF, o_acc[dt], 0, 0, 0);
            }
        }
    }

    // ---- epilogue: O / l ----
    float* Ob = O + ((size_t)b * S_ + (size_t)qt * BR) * D_;
    #pragma unroll
    for (int r = 0; r < 4; ++r) {
        float inv = 1.f / l_i[r];
        int row = wave * 16 + lk * 4 + r;
        #pragma unroll
        for (int dt = 0; dt < 4; ++dt) {
            Ob[row * D_ + dt * 16 + lm] = o_acc[dt][r] * inv;
        }
    }
}

extern "C" void kernel_launch(void* const* d_in, const int* in_sizes, int n_in,
                              void* d_out, int out_size, void* d_ws, size_t ws_size,
                              hipStream_t stream) {
    const float* Q = (const float*)d_in[0];
    const float* K = (const float*)d_in[1];
    const float* V = (const float*)d_in[2];
    float* O = (float*)d_out;
    dim3 grid(NQT, B_);
    fa_fwd<<<grid, 256, 0, stream>>>(Q, K, V, O);
}

// Round 2
// 119.976 us; speedup vs baseline: 1.6222x; 1.6222x over previous
//
#include <hip/hip_runtime.h>
#include <hip/hip_bf16.h>
#include <math.h>

#define B_  4
#define S_  4096
#define D_  64
#define BR  64
#define BC  64
#define NQT (S_/BR)   // 64
#define LDK 72        // K tile padded stride (shorts)
#define LDP 72        // P tile padded stride (shorts)

typedef __attribute__((ext_vector_type(8))) short bf16x8;   // 8 bf16 in 4 VGPRs
typedef __attribute__((ext_vector_type(4))) float f32x4;
typedef __attribute__((ext_vector_type(4))) short short4v;

static __device__ inline short f2bf(float f) {
    union { float f; unsigned u; } v; v.f = f;
    unsigned u = v.u;
    unsigned r = u + 0x7fff + ((u >> 16) & 1);   // round-to-nearest-even
    return (short)(r >> 16);
}

// ============================================================================
// Pass 1: one block = one (batch, q-tile, key-chunk). Writes unnormalized
// partial O (64x64 f32) + per-row (m, l) to workspace.
// Vt uses XOR-swizzled chunk layout: elem(d,key) at d*64 + ((key>>3)^((d>>2)&7))*8 + (key&7)
// -> staging scatter writes spread over 16 banks instead of 4.
// ============================================================================
__global__ __launch_bounds__(256) void fa_part(const float* __restrict__ Q,
                                               const float* __restrict__ K,
                                               const float* __restrict__ V,
                                               float* __restrict__ Opart,
                                               float* __restrict__ ML,
                                               int CH, int T)
{
    const int bid = blockIdx.x;
    const int b   = bid / T;
    int r = bid - b * T;
    int qt = NQT - 1;                       // jobs enumerated qt=63 down (big first)
    while (true) {
        int n = qt / CH + 1;
        if (r < n) break;
        r -= n; --qt;
    }
    const int kt0 = r * CH;
    const int kt1 = min(kt0 + CH, qt + 1);

    const int tid  = threadIdx.x;
    const int wave = tid >> 6;
    const int lane = tid & 63;
    const int lm   = lane & 15;
    const int lk   = lane >> 4;

    __shared__ short Ks[BC * LDK];   // [key][d]
    __shared__ short Vt[D_ * 64];    // [d][key], swizzled chunks
    __shared__ short Ps[BR * LDP];   // [q][key]

    const float* Qb = Q + ((size_t)b * S_ + (size_t)qt * BR) * D_;
    const float* Kb = K + (size_t)b * S_ * D_;
    const float* Vb = V + (size_t)b * S_ * D_;

    // Q fragments, pre-scaled by 1/8 (exact)
    bf16x8 qA[2];
    {
        const float* qp = Qb + (wave * 16 + lm) * D_;
        #pragma unroll
        for (int h = 0; h < 2; ++h) {
            const float* p = qp + h * 32 + lk * 8;
            #pragma unroll
            for (int j = 0; j < 8; ++j) qA[h][j] = f2bf(p[j] * 0.125f);
        }
    }

    float m_i[4], l_i[4];
    f32x4 o_acc[4];
    #pragma unroll
    for (int rr = 0; rr < 4; ++rr) { m_i[rr] = -INFINITY; l_i[rr] = 0.f; }
    #pragma unroll
    for (int dt = 0; dt < 4; ++dt) o_acc[dt] = (f32x4){0.f, 0.f, 0.f, 0.f};

    for (int kt = kt0; kt < kt1; ++kt) {
        __syncthreads();
        // ---- stage K tile and swizzled V^T tile (bf16) ----
        #pragma unroll
        for (int rr = 0; rr < 4; ++rr) {
            int i   = tid + rr * 256;
            int row = i >> 4;
            int c4  = (i & 15) * 4;
            const size_t gbase = ((size_t)(kt * BC + row)) * D_ + c4;
            f32x4 kv = *(const f32x4*)(Kb + gbase);
            short4v ks;
            ks[0] = f2bf(kv[0]); ks[1] = f2bf(kv[1]);
            ks[2] = f2bf(kv[2]); ks[3] = f2bf(kv[3]);
            *(short4v*)&Ks[row * LDK + c4] = ks;
            f32x4 vv = *(const f32x4*)(Vb + gbase);
            const int sw  = (i & 15) & 7;                    // (d>>2)&7 for d=c4..c4+3
            const int pos = (((row >> 3) ^ sw) << 3) + (row & 7);
            #pragma unroll
            for (int j = 0; j < 4; ++j)
                Vt[(c4 + j) * 64 + pos] = f2bf(vv[j]);
        }
        __syncthreads();

        // ---- S = Q K^T ----
        f32x4 s[4];
        #pragma unroll
        for (int ct = 0; ct < 4; ++ct) {
            f32x4 acc = (f32x4){0.f, 0.f, 0.f, 0.f};
            #pragma unroll
            for (int h = 0; h < 2; ++h) {
                bf16x8 bF = *(const bf16x8*)&Ks[(ct * 16 + lm) * LDK + h * 32 + lk * 8];
                acc = __builtin_amdgcn_mfma_f32_16x16x32_bf16(qA[h], bF, acc, 0, 0, 0);
            }
            s[ct] = acc;
        }

        // ---- causal mask on diagonal tile ----
        if (kt == qt) {
            #pragma unroll
            for (int ct = 0; ct < 4; ++ct) {
                #pragma unroll
                for (int rr = 0; rr < 4; ++rr) {
                    int qrow = wave * 16 + lk * 4 + rr;
                    int kcol = ct * 16 + lm;
                    if (kcol > qrow) s[ct][rr] = -INFINITY;
                }
            }
        }

        // ---- online softmax ----
        float alpha[4];
        #pragma unroll
        for (int rr = 0; rr < 4; ++rr) {
            float mx = fmaxf(fmaxf(s[0][rr], s[1][rr]), fmaxf(s[2][rr], s[3][rr]));
            mx = fmaxf(mx, __shfl_xor(mx, 1));
            mx = fmaxf(mx, __shfl_xor(mx, 2));
            mx = fmaxf(mx, __shfl_xor(mx, 4));
            mx = fmaxf(mx, __shfl_xor(mx, 8));
            float mn = fmaxf(m_i[rr], mx);
            alpha[rr] = __expf(m_i[rr] - mn);
            m_i[rr] = mn;
        }
        float rsum[4] = {0.f, 0.f, 0.f, 0.f};
        #pragma unroll
        for (int ct = 0; ct < 4; ++ct) {
            #pragma unroll
            for (int rr = 0; rr < 4; ++rr) {
                float p = __expf(s[ct][rr] - m_i[rr]);
                s[ct][rr] = p;
                rsum[rr] += p;
            }
        }
        #pragma unroll
        for (int rr = 0; rr < 4; ++rr) {
            float rs = rsum[rr];
            rs += __shfl_xor(rs, 1);
            rs += __shfl_xor(rs, 2);
            rs += __shfl_xor(rs, 4);
            rs += __shfl_xor(rs, 8);
            l_i[rr] = l_i[rr] * alpha[rr] + rs;
        }
        // P -> LDS (per-wave region, wave-local, no barrier)
        #pragma unroll
        for (int ct = 0; ct < 4; ++ct) {
            #pragma unroll
            for (int rr = 0; rr < 4; ++rr) {
                Ps[(wave * 16 + lk * 4 + rr) * LDP + ct * 16 + lm] = f2bf(s[ct][rr]);
            }
        }
        #pragma unroll
        for (int dt = 0; dt < 4; ++dt) {
            #pragma unroll
            for (int rr = 0; rr < 4; ++rr) o_acc[dt][rr] *= alpha[rr];
        }
        // ---- O += P V ----
        #pragma unroll
        for (int dt = 0; dt < 4; ++dt) {
            const int ss = (4 * dt + (lm >> 2)) & 7;
            #pragma unroll
            for (int kh = 0; kh < 2; ++kh) {
                bf16x8 aF = *(const bf16x8*)&Ps[(wave * 16 + lm) * LDP + kh * 32 + lk * 8];
                bf16x8 bF = *(const bf16x8*)&Vt[(dt * 16 + lm) * 64 + (((kh * 4 + lk) ^ ss) << 3)];
                o_acc[dt] = __builtin_amdgcn_mfma_f32_16x16x32_bf16(aF, bF, o_acc[dt], 0, 0, 0);
            }
        }
    }

    // ---- epilogue: unnormalized partials + (m, l) ----
    float* Op = Opart + (size_t)bid * (BR * D_);
    #pragma unroll
    for (int rr = 0; rr < 4; ++rr) {
        int row = wave * 16 + lk * 4 + rr;
        #pragma unroll
        for (int dt = 0; dt < 4; ++dt)
            Op[row * D_ + dt * 16 + lm] = o_acc[dt][rr];
        if (lm == 0) {
            ML[(size_t)bid * (BR * 2) + row * 2]     = m_i[rr];
            ML[(size_t)bid * (BR * 2) + row * 2 + 1] = l_i[rr];
        }
    }
}

// ============================================================================
// Pass 2: merge partials. One thread per float4 of output.
// ============================================================================
__global__ __launch_bounds__(256) void fa_combine(const float* __restrict__ Opart,
                                                  const float* __restrict__ ML,
                                                  float* __restrict__ O,
                                                  int CH, int T)
{
    const int idx = blockIdx.x * 256 + threadIdx.x;       // 0 .. B*S*16-1
    const int b   = idx / (S_ * 16);
    const int rem = idx - b * (S_ * 16);
    const int q   = rem >> 4;
    const int d4  = (rem & 15) << 2;
    const int qt  = q >> 6;
    const int rit = q & 63;

    // F(qt+1) = #chunks for q-tiles < qt+1 ; jobs are enumerated qt=63 first
    const int x = qt + 1;
    const int a = x / CH, rr = x - a * CH;
    const int F = x + CH * (a * (a - 1) / 2) + rr * a;
    const int base = b * T + (T - F);
    const int nch  = qt / CH + 1;

    float M = -INFINITY;
    for (int c = 0; c < nch; ++c)
        M = fmaxf(M, ML[(size_t)(base + c) * (BR * 2) + rit * 2]);

    float L = 0.f;
    f32x4 acc = (f32x4){0.f, 0.f, 0.f, 0.f};
    for (int c = 0; c < nch; ++c) {
        float m = ML[(size_t)(base + c) * (BR * 2) + rit * 2];
        float l = ML[(size_t)(base + c) * (BR * 2) + rit * 2 + 1];
        float w = __expf(m - M);
        L += l * w;
        f32x4 o = *(const f32x4*)(Opart + (size_t)(base + c) * (BR * D_) + rit * D_ + d4);
        acc[0] += o[0] * w; acc[1] += o[1] * w;
        acc[2] += o[2] * w; acc[3] += o[3] * w;
    }
    float inv = 1.f / L;
    f32x4 outv;
    outv[0] = acc[0] * inv; outv[1] = acc[1] * inv;
    outv[2] = acc[2] * inv; outv[3] = acc[3] * inv;
    *(f32x4*)(O + (size_t)idx * 4) = outv;
}

// ============================================================================
// Fallback (round-1 kernel, known good) in case ws_size is tiny.
// ============================================================================
__global__ __launch_bounds__(256) void fa_fwd(const float* __restrict__ Q,
                                              const float* __restrict__ K,
                                              const float* __restrict__ V,
                                              float* __restrict__ O)
{
    const int qt   = (gridDim.x - 1) - blockIdx.x;
    const int b    = blockIdx.y;
    const int tid  = threadIdx.x;
    const int wave = tid >> 6;
    const int lane = tid & 63;
    const int lm   = lane & 15;
    const int lk   = lane >> 4;

    __shared__ short Ks[BC * LDK];
    __shared__ short Vt[D_ * 72];
    __shared__ short Ps[BR * LDP];

    const float* Qb = Q + ((size_t)b * S_ + (size_t)qt * BR) * D_;
    const float* Kb = K + (size_t)b * S_ * D_;
    const float* Vb = V + (size_t)b * S_ * D_;

    bf16x8 qA[2];
    {
        const float* qp = Qb + (wave * 16 + lm) * D_;
        #pragma unroll
        for (int h = 0; h < 2; ++h) {
            const float* p = qp + h * 32 + lk * 8;
            #pragma unroll
            for (int j = 0; j < 8; ++j) qA[h][j] = f2bf(p[j] * 0.125f);
        }
    }
    float m_i[4], l_i[4];
    f32x4 o_acc[4];
    #pragma unroll
    for (int rr = 0; rr < 4; ++rr) { m_i[rr] = -INFINITY; l_i[rr] = 0.f; }
    #pragma unroll
    for (int dt = 0; dt < 4; ++dt) o_acc[dt] = (f32x4){0.f, 0.f, 0.f, 0.f};

    const int n_kt = qt + 1;
    for (int kt = 0; kt < n_kt; ++kt) {
        __syncthreads();
        #pragma unroll
        for (int rr = 0; rr < 4; ++rr) {
            int i   = tid + rr * 256;
            int row = i >> 4;
            int c4  = (i & 15) * 4;
            const size_t gbase = ((size_t)(kt * BC + row)) * D_ + c4;
            f32x4 kv = *(const f32x4*)(Kb + gbase);
            short4v ks;
            ks[0] = f2bf(kv[0]); ks[1] = f2bf(kv[1]);
            ks[2] = f2bf(kv[2]); ks[3] = f2bf(kv[3]);
            *(short4v*)&Ks[row * LDK + c4] = ks;
            f32x4 vv = *(const f32x4*)(Vb + gbase);
            Vt[(c4 + 0) * 72 + row] = f2bf(vv[0]);
            Vt[(c4 + 1) * 72 + row] = f2bf(vv[1]);
            Vt[(c4 + 2) * 72 + row] = f2bf(vv[2]);
            Vt[(c4 + 3) * 72 + row] = f2bf(vv[3]);
        }
        __syncthreads();
        f32x4 s[4];
        #pragma unroll
        for (int ct = 0; ct < 4; ++ct) {
            f32x4 acc = (f32x4){0.f, 0.f, 0.f, 0.f};
            #pragma unroll
            for (int h = 0; h < 2; ++h) {
                bf16x8 bF = *(const bf16x8*)&Ks[(ct * 16 + lm) * LDK + h * 32 + lk * 8];
                acc = __builtin_amdgcn_mfma_f32_16x16x32_bf16(qA[h], bF, acc, 0, 0, 0);
            }
            s[ct] = acc;
        }
        if (kt == qt) {
            #pragma unroll
            for (int ct = 0; ct < 4; ++ct) {
                #pragma unroll
                for (int rr = 0; rr < 4; ++rr) {
                    int qrow = wave * 16 + lk * 4 + rr;
                    int kcol = ct * 16 + lm;
                    if (kcol > qrow) s[ct][rr] = -INFINITY;
                }
            }
        }
        float alpha[4];
        #pragma unroll
        for (int rr = 0; rr < 4; ++rr) {
            float mx = fmaxf(fmaxf(s[0][rr], s[1][rr]), fmaxf(s[2][rr], s[3][rr]));
            mx = fmaxf(mx, __shfl_xor(mx, 1));
            mx = fmaxf(mx, __shfl_xor(mx, 2));
            mx = fmaxf(mx, __shfl_xor(mx, 4));
            mx = fmaxf(mx, __shfl_xor(mx, 8));
            float mn = fmaxf(m_i[rr], mx);
            alpha[rr] = __expf(m_i[rr] - mn);
            m_i[rr] = mn;
        }
        float rsum[4] = {0.f, 0.f, 0.f, 0.f};
        #pragma unroll
        for (int ct = 0; ct < 4; ++ct) {
            #pragma unroll
            for (int rr = 0; rr < 4; ++rr) {
                float p = __expf(s[ct][rr] - m_i[rr]);
                s[ct][rr] = p;
                rsum[rr] += p;
            }
        }
        #pragma unroll
        for (int rr = 0; rr < 4; ++rr) {
            float rs = rsum[rr];
            rs += __shfl_xor(rs, 1);
            rs += __shfl_xor(rs, 2);
            rs += __shfl_xor(rs, 4);
            rs += __shfl_xor(rs, 8);
            l_i[rr] = l_i[rr] * alpha[rr] + rs;
        }
        #pragma unroll
        for (int ct = 0; ct < 4; ++ct) {
            #pragma unroll
            for (int rr = 0; rr < 4; ++rr) {
                Ps[(wave * 16 + lk * 4 + rr) * LDP + ct * 16 + lm] = f2bf(s[ct][rr]);
            }
        }
        #pragma unroll
        for (int dt = 0; dt < 4; ++dt) {
            #pragma unroll
            for (int rr = 0; rr < 4; ++rr) o_acc[dt][rr] *= alpha[rr];
        }
        #pragma unroll
        for (int dt = 0; dt < 4; ++dt) {
            #pragma unroll
            for (int kh = 0; kh < 2; ++kh) {
                bf16x8 aF = *(const bf16x8*)&Ps[(wave * 16 + lm) * LDP + kh * 32 + lk * 8];
                bf16x8 bF = *(const bf16x8*)&Vt[(dt * 16 + lm) * 72 + kh * 32 + lk * 8];
                o_acc[dt] = __builtin_amdgcn_mfma_f32_16x16x32_bf16(aF, bF, o_acc[dt], 0, 0, 0);
            }
        }
    }
    float* Ob = O + ((size_t)b * S_ + (size_t)qt * BR) * D_;
    #pragma unroll
    for (int rr = 0; rr < 4; ++rr) {
        float inv = 1.f / l_i[rr];
        int row = wave * 16 + lk * 4 + rr;
        #pragma unroll
        for (int dt = 0; dt < 4; ++dt) {
            Ob[row * D_ + dt * 16 + lm] = o_acc[dt][rr] * inv;
        }
    }
}

extern "C" void kernel_launch(void* const* d_in, const int* in_sizes, int n_in,
                              void* d_out, int out_size, void* d_ws, size_t ws_size,
                              hipStream_t stream) {
    const float* Q = (const float*)d_in[0];
    const float* K = (const float*)d_in[1];
    const float* V = (const float*)d_in[2];
    float* O = (float*)d_out;

    // pick smallest chunk size whose workspace fits
    int CH = 0, T = 0;
    const int chs[4] = {8, 16, 32, 64};
    for (int k = 0; k < 4; ++k) {
        int c = chs[k];
        int t = 0;
        for (int qt = 0; qt < NQT; ++qt) t += qt / c + 1;
        size_t need = (size_t)B_ * t * (BR * D_ + BR * 2) * sizeof(float);
        if (need <= ws_size) { CH = c; T = t; break; }
    }
    if (CH == 0) {
        dim3 grid(NQT, B_);
        fa_fwd<<<grid, 256, 0, stream>>>(Q, K, V, O);
        return;
    }
    float* Opart = (float*)d_ws;
    float* ML    = Opart + (size_t)B_ * T * BR * D_;
    fa_part<<<dim3(B_ * T), 256, 0, stream>>>(Q, K, V, Opart, ML, CH, T);
    fa_combine<<<dim3((B_ * S_ * 16) / 256), 256, 0, stream>>>(Opart, ML, O, CH, T);
}

// Round 4
// 118.027 us; speedup vs baseline: 1.6490x; 1.0165x over previous
//
#include <hip/hip_runtime.h>
#include <hip/hip_bf16.h>
#include <math.h>

#define B_  4
#define S_  4096
#define D_  64
#define BR  64
#define BC  64
#define NQT (S_/BR)   // 64
#define LDP 68        // P tile padded stride (shorts): 136 B row -> writes spread 32 banks
#define QSC 0.18033688f   // 0.125 * log2(e): folds softmax scale AND exp->exp2 conversion

typedef __attribute__((ext_vector_type(8))) short bf16x8;
typedef __attribute__((ext_vector_type(4))) float f32x4;
typedef __attribute__((ext_vector_type(2))) float f32x2;
typedef __attribute__((ext_vector_type(4))) short short4v;

static __device__ inline short f2bf(float f) {
    union { float f; unsigned u; } v; v.f = f;
    unsigned u = v.u;
    unsigned r = u + 0x7fff + ((u >> 16) & 1);
    return (short)(r >> 16);
}
static __device__ inline float bf2f(short s) {
    union { unsigned u; float f; } v; v.u = ((unsigned)(unsigned short)s) << 16;
    return v.f;
}
static __device__ inline void gload_lds16(const void* g, void* l) {
    __builtin_amdgcn_global_load_lds((const __attribute__((address_space(1))) void*)g,
                                     (__attribute__((address_space(3))) void*)l, 16, 0, 0);
}

// ============================================================================
// Prep: Q*QSC -> bf16 ; K -> bf16 ; V -> V^T bf16 ([b][d][key]).
// Grid 256 blocks x 256 thr; each block = one (b, 64-row s-tile).
// ============================================================================
__global__ __launch_bounds__(256) void fa_prep(const float* __restrict__ Q,
                                               const float* __restrict__ K,
                                               const float* __restrict__ V,
                                               short* __restrict__ Qbf,
                                               short* __restrict__ Kbf,
                                               short* __restrict__ Vtbf)
{
    const int b   = blockIdx.x >> 6;
    const int st  = blockIdx.x & 63;
    const int tid = threadIdx.x;
    __shared__ short Vs[64 * 72];

    const size_t tbase = ((size_t)b * S_ + (size_t)st * 64) * D_;
    #pragma unroll
    for (int rr = 0; rr < 4; ++rr) {
        int i = tid + rr * 256;            // f32x4 chunk 0..1023 within tile
        size_t e = tbase + (size_t)i * 4;
        f32x4 q = *(const f32x4*)(Q + e);
        short4v qs;
        qs[0] = f2bf(q[0] * QSC); qs[1] = f2bf(q[1] * QSC);
        qs[2] = f2bf(q[2] * QSC); qs[3] = f2bf(q[3] * QSC);
        *(short4v*)(Qbf + e) = qs;
        f32x4 k = *(const f32x4*)(K + e);
        short4v ks;
        ks[0] = f2bf(k[0]); ks[1] = f2bf(k[1]);
        ks[2] = f2bf(k[2]); ks[3] = f2bf(k[3]);
        *(short4v*)(Kbf + e) = ks;
        f32x4 v = *(const f32x4*)(V + e);
        int key = i >> 4, d4 = (i & 15) * 4;
        Vs[(d4 + 0) * 72 + key] = f2bf(v[0]);
        Vs[(d4 + 1) * 72 + key] = f2bf(v[1]);
        Vs[(d4 + 2) * 72 + key] = f2bf(v[2]);
        Vs[(d4 + 3) * 72 + key] = f2bf(v[3]);
    }
    __syncthreads();
    #pragma unroll
    for (int cc = 0; cc < 2; ++cc) {
        int c = tid + cc * 256;            // 16B chunk 0..511
        int d = c >> 3, sg = c & 7;
        bf16x8 row = *(const bf16x8*)&Vs[d * 72 + sg * 8];
        *(bf16x8*)(Vtbf + ((size_t)(b * D_ + d)) * S_ + (size_t)st * 64 + sg * 8) = row;
    }
}

// ============================================================================
// Pass 1: one block = (b, qt, key-chunk). bf16 inputs, global_load_lds staging
// with XOR-seg swizzle: data(row,seg) lives at LDS row*128B + (seg^(row&7))*16B.
// MFMA b128 fragment reads then hit the 8-access/bank floor.
// ============================================================================
__global__ __launch_bounds__(256) void fa_part(const short* __restrict__ Qbf,
                                               const short* __restrict__ Kbf,
                                               const short* __restrict__ Vtbf,
                                               short* __restrict__ Opart,
                                               float* __restrict__ ML,
                                               int CH, int T)
{
    const int bid = blockIdx.x;
    const int b   = bid / T;
    int r = bid - b * T;
    int qt = NQT - 1;                       // jobs enumerated qt=63 down (big first)
    while (true) {
        int n = qt / CH + 1;
        if (r < n) break;
        r -= n; --qt;
    }
    const int kt0 = r * CH;
    const int kt1 = min(kt0 + CH, qt + 1);

    const int tid  = threadIdx.x;
    const int wave = tid >> 6;
    const int lane = tid & 63;
    const int lm   = lane & 15;
    const int lk   = lane >> 4;

    __shared__ short Ks[64 * 64];   // [key][d], seg-swizzled
    __shared__ short Vt[64 * 64];   // [d][key], seg-swizzled
    __shared__ short Ps[64 * LDP];  // [q][key]

    // Q fragments (already bf16, pre-scaled, exp2-domain)
    bf16x8 qA[2];
    {
        const short* qp = Qbf + ((size_t)(b * S_ + qt * 64 + wave * 16 + lm)) * D_;
        qA[0] = *(const bf16x8*)(qp + lk * 8);
        qA[1] = *(const bf16x8*)(qp + 32 + lk * 8);
    }

    // staging source/dest pointers: slot s = c*256+tid -> row=s>>3, seg'=s&7
    const char* kgp[2]; const char* vgp[2];
    const short* klp[2]; const short* vlp[2];
    #pragma unroll
    for (int c = 0; c < 2; ++c) {
        int s = c * 256 + tid;
        int row = s >> 3, segp = s & 7, seg = segp ^ (row & 7);
        kgp[c] = (const char*)(Kbf + (size_t)b * S_ * D_)
               + (size_t)(kt0 * 64 + row) * 128 + seg * 16;
        vgp[c] = (const char*)(Vtbf + ((size_t)(b * D_ + row)) * S_)
               + (size_t)kt0 * 128 + seg * 16;
        klp[c] = &Ks[(c * 256 + wave * 64) * 8];   // wave-uniform; HW adds lane*16
        vlp[c] = &Vt[(c * 256 + wave * 64) * 8];
    }

    float m_i[4], l_i[4];
    f32x4 o_acc[4];
    #pragma unroll
    for (int rr = 0; rr < 4; ++rr) { m_i[rr] = -INFINITY; l_i[rr] = 0.f; }
    #pragma unroll
    for (int dt = 0; dt < 4; ++dt) o_acc[dt] = (f32x4){0.f, 0.f, 0.f, 0.f};

    for (int kt = kt0; kt < kt1; ++kt) {
        __syncthreads();   // prior tile's readers done before overwrite
        #pragma unroll
        for (int c = 0; c < 2; ++c) {
            gload_lds16(kgp[c], (void*)klp[c]);
            gload_lds16(vgp[c], (void*)vlp[c]);
            kgp[c] += 8192;   // next key-tile of K
            vgp[c] += 128;    // next key-tile within each V^T d-row
        }
        __syncthreads();   // drains vmcnt: staged data visible

        // ---- S = Q K^T (exp2-domain) ----
        f32x4 s4[4];
        #pragma unroll
        for (int ct = 0; ct < 4; ++ct) {
            f32x4 acc = (f32x4){0.f, 0.f, 0.f, 0.f};
            #pragma unroll
            for (int h = 0; h < 2; ++h) {
                int seg = (h * 4 + lk) ^ (lm & 7);
                bf16x8 bF = *(const bf16x8*)&Ks[(ct * 16 + lm) * 64 + seg * 8];
                acc = __builtin_amdgcn_mfma_f32_16x16x32_bf16(qA[h], bF, acc, 0, 0, 0);
            }
            s4[ct] = acc;
        }

        // ---- causal mask on diagonal tile ----
        if (kt == qt) {
            #pragma unroll
            for (int ct = 0; ct < 4; ++ct) {
                #pragma unroll
                for (int rr = 0; rr < 4; ++rr) {
                    int qrow = wave * 16 + lk * 4 + rr;
                    int kcol = ct * 16 + lm;
                    if (kcol > qrow) s4[ct][rr] = -INFINITY;
                }
            }
        }

        // ---- online softmax (exp2-domain) ----
        float alpha[4];
        #pragma unroll
        for (int rr = 0; rr < 4; ++rr) {
            float mx = fmaxf(fmaxf(s4[0][rr], s4[1][rr]), fmaxf(s4[2][rr], s4[3][rr]));
            mx = fmaxf(mx, __shfl_xor(mx, 1));
            mx = fmaxf(mx, __shfl_xor(mx, 2));
            mx = fmaxf(mx, __shfl_xor(mx, 4));
            mx = fmaxf(mx, __shfl_xor(mx, 8));
            float mn = fmaxf(m_i[rr], mx);
            alpha[rr] = exp2f(m_i[rr] - mn);
            m_i[rr] = mn;
        }
        float rsum[4] = {0.f, 0.f, 0.f, 0.f};
        #pragma unroll
        for (int ct = 0; ct < 4; ++ct) {
            #pragma unroll
            for (int rr = 0; rr < 4; ++rr) {
                float p = exp2f(s4[ct][rr] - m_i[rr]);
                s4[ct][rr] = p;
                rsum[rr] += p;
            }
        }
        #pragma unroll
        for (int rr = 0; rr < 4; ++rr) {
            float rs = rsum[rr];
            rs += __shfl_xor(rs, 1);
            rs += __shfl_xor(rs, 2);
            rs += __shfl_xor(rs, 4);
            rs += __shfl_xor(rs, 8);
            l_i[rr] = l_i[rr] * alpha[rr] + rs;
        }
        // P -> LDS (per-wave rows; wave-local)
        #pragma unroll
        for (int ct = 0; ct < 4; ++ct) {
            #pragma unroll
            for (int rr = 0; rr < 4; ++rr) {
                Ps[(wave * 16 + lk * 4 + rr) * LDP + ct * 16 + lm] = f2bf(s4[ct][rr]);
            }
        }
        #pragma unroll
        for (int dt = 0; dt < 4; ++dt) {
            #pragma unroll
            for (int rr = 0; rr < 4; ++rr) o_acc[dt][rr] *= alpha[rr];
        }
        // ---- O += P V ----
        bf16x8 aF[2];
        #pragma unroll
        for (int kh = 0; kh < 2; ++kh)
            aF[kh] = *(const bf16x8*)&Ps[(wave * 16 + lm) * LDP + kh * 32 + lk * 8];
        #pragma unroll
        for (int dt = 0; dt < 4; ++dt) {
            #pragma unroll
            for (int kh = 0; kh < 2; ++kh) {
                int seg = (kh * 4 + lk) ^ (lm & 7);
                bf16x8 bF = *(const bf16x8*)&Vt[(dt * 16 + lm) * 64 + seg * 8];
                o_acc[dt] = __builtin_amdgcn_mfma_f32_16x16x32_bf16(aF[kh], bF, o_acc[dt], 0, 0, 0);
            }
        }
    }

    // ---- epilogue: bf16 unnormalized partials + (m, l) ----
    short* Op = Opart + (size_t)bid * (BR * D_);
    #pragma unroll
    for (int rr = 0; rr < 4; ++rr) {
        int row = wave * 16 + lk * 4 + rr;
        #pragma unroll
        for (int dt = 0; dt < 4; ++dt)
            Op[row * D_ + dt * 16 + lm] = f2bf(o_acc[dt][rr]);
        if (lm == 0) {
            ML[(size_t)bid * (BR * 2) + row * 2]     = m_i[rr];
            ML[(size_t)bid * (BR * 2) + row * 2 + 1] = l_i[rr];
        }
    }
}

// ============================================================================
// Pass 2: merge bf16 partials. One thread per float4 of output.
// ============================================================================
__global__ __launch_bounds__(256) void fa_combine(const short* __restrict__ Opart,
                                                  const float* __restrict__ ML,
                                                  float* __restrict__ O,
                                                  int CH, int T)
{
    const int idx = blockIdx.x * 256 + threadIdx.x;
    const int b   = idx / (S_ * 16);
    const int rem = idx - b * (S_ * 16);
    const int q   = rem >> 4;
    const int d4  = (rem & 15) << 2;
    const int qt  = q >> 6;
    const int rit = q & 63;

    const int x = qt + 1;
    const int a = x / CH, rr = x - a * CH;
    const int F = x + CH * (a * (a - 1) / 2) + rr * a;
    const int base = b * T + (T - F);
    const int nch  = qt / CH + 1;

    float M = -INFINITY;
    for (int c = 0; c < nch; ++c) {
        f32x2 ml = *(const f32x2*)(ML + (size_t)(base + c) * (BR * 2) + rit * 2);
        M = fmaxf(M, ml[0]);
    }
    float L = 0.f;
    f32x4 acc = (f32x4){0.f, 0.f, 0.f, 0.f};
    for (int c = 0; c < nch; ++c) {
        f32x2 ml = *(const f32x2*)(ML + (size_t)(base + c) * (BR * 2) + rit * 2);
        float w = exp2f(ml[0] - M);
        L += ml[1] * w;
        short4v o = *(const short4v*)(Opart + (size_t)(base + c) * (BR * D_) + rit * D_ + d4);
        acc[0] += bf2f(o[0]) * w; acc[1] += bf2f(o[1]) * w;
        acc[2] += bf2f(o[2]) * w; acc[3] += bf2f(o[3]) * w;
    }
    float inv = 1.f / L;
    f32x4 outv;
    outv[0] = acc[0] * inv; outv[1] = acc[1] * inv;
    outv[2] = acc[2] * inv; outv[3] = acc[3] * inv;
    *(f32x4*)(O + (size_t)idx * 4) = outv;
}

// ============================================================================
// Fallback (round-1 monolithic kernel, known good) if ws is too small.
// ============================================================================
__global__ __launch_bounds__(256) void fa_fwd(const float* __restrict__ Q,
                                              const float* __restrict__ K,
                                              const float* __restrict__ V,
                                              float* __restrict__ O)
{
    const int qt   = (gridDim.x - 1) - blockIdx.x;
    const int b    = blockIdx.y;
    const int tid  = threadIdx.x;
    const int wave = tid >> 6;
    const int lane = tid & 63;
    const int lm   = lane & 15;
    const int lk   = lane >> 4;

    __shared__ short Ks[64 * 72];
    __shared__ short Vt[64 * 72];
    __shared__ short Ps[64 * 72];

    const float* Qb = Q + ((size_t)b * S_ + (size_t)qt * BR) * D_;
    const float* Kb = K + (size_t)b * S_ * D_;
    const float* Vb = V + (size_t)b * S_ * D_;

    bf16x8 qA[2];
    {
        const float* qp = Qb + (wave * 16 + lm) * D_;
        #pragma unroll
        for (int h = 0; h < 2; ++h) {
            const float* p = qp + h * 32 + lk * 8;
            #pragma unroll
            for (int j = 0; j < 8; ++j) qA[h][j] = f2bf(p[j] * 0.125f);
        }
    }
    float m_i[4], l_i[4];
    f32x4 o_acc[4];
    #pragma unroll
    for (int rr = 0; rr < 4; ++rr) { m_i[rr] = -INFINITY; l_i[rr] = 0.f; }
    #pragma unroll
    for (int dt = 0; dt < 4; ++dt) o_acc[dt] = (f32x4){0.f, 0.f, 0.f, 0.f};

    const int n_kt = qt + 1;
    for (int kt = 0; kt < n_kt; ++kt) {
        __syncthreads();
        #pragma unroll
        for (int rr = 0; rr < 4; ++rr) {
            int i   = tid + rr * 256;
            int row = i >> 4;
            int c4  = (i & 15) * 4;
            const size_t gbase = ((size_t)(kt * BC + row)) * D_ + c4;
            f32x4 kv = *(const f32x4*)(Kb + gbase);
            short4v ks;
            ks[0] = f2bf(kv[0]); ks[1] = f2bf(kv[1]);
            ks[2] = f2bf(kv[2]); ks[3] = f2bf(kv[3]);
            *(short4v*)&Ks[row * 72 + c4] = ks;
            f32x4 vv = *(const f32x4*)(Vb + gbase);
            Vt[(c4 + 0) * 72 + row] = f2bf(vv[0]);
            Vt[(c4 + 1) * 72 + row] = f2bf(vv[1]);
            Vt[(c4 + 2) * 72 + row] = f2bf(vv[2]);
            Vt[(c4 + 3) * 72 + row] = f2bf(vv[3]);
        }
        __syncthreads();
        f32x4 s4[4];
        #pragma unroll
        for (int ct = 0; ct < 4; ++ct) {
            f32x4 acc = (f32x4){0.f, 0.f, 0.f, 0.f};
            #pragma unroll
            for (int h = 0; h < 2; ++h) {
                bf16x8 bF = *(const bf16x8*)&Ks[(ct * 16 + lm) * 72 + h * 32 + lk * 8];
                acc = __builtin_amdgcn_mfma_f32_16x16x32_bf16(qA[h], bF, acc, 0, 0, 0);
            }
            s4[ct] = acc;
        }
        if (kt == qt) {
            #pragma unroll
            for (int ct = 0; ct < 4; ++ct) {
                #pragma unroll
                for (int rr = 0; rr < 4; ++rr) {
                    int qrow = wave * 16 + lk * 4 + rr;
                    int kcol = ct * 16 + lm;
                    if (kcol > qrow) s4[ct][rr] = -INFINITY;
                }
            }
        }
        float alpha[4];
        #pragma unroll
        for (int rr = 0; rr < 4; ++rr) {
            float mx = fmaxf(fmaxf(s4[0][rr], s4[1][rr]), fmaxf(s4[2][rr], s4[3][rr]));
            mx = fmaxf(mx, __shfl_xor(mx, 1));
            mx = fmaxf(mx, __shfl_xor(mx, 2));
            mx = fmaxf(mx, __shfl_xor(mx, 4));
            mx = fmaxf(mx, __shfl_xor(mx, 8));
            float mn = fmaxf(m_i[rr], mx);
            alpha[rr] = __expf(m_i[rr] - mn);
            m_i[rr] = mn;
        }
        float rsum[4] = {0.f, 0.f, 0.f, 0.f};
        #pragma unroll
        for (int ct = 0; ct < 4; ++ct) {
            #pragma unroll
            for (int rr = 0; rr < 4; ++rr) {
                float p = __expf(s4[ct][rr] - m_i[rr]);
                s4[ct][rr] = p;
                rsum[rr] += p;
            }
        }
        #pragma unroll
        for (int rr = 0; rr < 4; ++rr) {
            float rs = rsum[rr];
            rs += __shfl_xor(rs, 1);
            rs += __shfl_xor(rs, 2);
            rs += __shfl_xor(rs, 4);
            rs += __shfl_xor(rs, 8);
            l_i[rr] = l_i[rr] * alpha[rr] + rs;
        }
        #pragma unroll
        for (int ct = 0; ct < 4; ++ct) {
            #pragma unroll
            for (int rr = 0; rr < 4; ++rr) {
                Ps[(wave * 16 + lk * 4 + rr) * 72 + ct * 16 + lm] = f2bf(s4[ct][rr]);
            }
        }
        #pragma unroll
        for (int dt = 0; dt < 4; ++dt) {
            #pragma unroll
            for (int rr = 0; rr < 4; ++rr) o_acc[dt][rr] *= alpha[rr];
        }
        #pragma unroll
        for (int dt = 0; dt < 4; ++dt) {
            #pragma unroll
            for (int kh = 0; kh < 2; ++kh) {
                bf16x8 aF = *(const bf16x8*)&Ps[(wave * 16 + lm) * 72 + kh * 32 + lk * 8];
                bf16x8 bF = *(const bf16x8*)&Vt[(dt * 16 + lm) * 72 + kh * 32 + lk * 8];
                o_acc[dt] = __builtin_amdgcn_mfma_f32_16x16x32_bf16(aF, bF, o_acc[dt], 0, 0, 0);
            }
        }
    }
    float* Ob = O + ((size_t)b * S_ + (size_t)qt * BR) * D_;
    #pragma unroll
    for (int rr = 0; rr < 4; ++rr) {
        float inv = 1.f / l_i[rr];
        int row = wave * 16 + lk * 4 + rr;
        #pragma unroll
        for (int dt = 0; dt < 4; ++dt) {
            Ob[row * D_ + dt * 16 + lm] = o_acc[dt][rr] * inv;
        }
    }
}

extern "C" void kernel_launch(void* const* d_in, const int* in_sizes, int n_in,
                              void* d_out, int out_size, void* d_ws, size_t ws_size,
                              hipStream_t stream) {
    const float* Q = (const float*)d_in[0];
    const float* K = (const float*)d_in[1];
    const float* V = (const float*)d_in[2];
    float* O = (float*)d_out;

    const size_t convShorts = (size_t)B_ * S_ * D_;      // per buffer (1 Mi shorts)
    int CH = 0, T = 0;
    const int chs[4] = {8, 16, 32, 64};
    for (int k = 0; k < 4; ++k) {
        int c = chs[k];
        int t = 0;
        for (int qt = 0; qt < NQT; ++qt) t += qt / c + 1;
        size_t need = 3 * convShorts * 2                          // Qbf/Kbf/Vtbf
                    + (size_t)B_ * t * (BR * D_) * 2              // Opart bf16
                    + (size_t)B_ * t * (BR * 2) * 4;              // ML f32
        if (need <= ws_size) { CH = c; T = t; break; }
    }
    if (CH == 0) {
        dim3 grid(NQT, B_);
        fa_fwd<<<grid, 256, 0, stream>>>(Q, K, V, O);
        return;
    }
    short* Qbf   = (short*)d_ws;
    short* Kbf   = Qbf + convShorts;
    short* Vtbf  = Kbf + convShorts;
    short* Opart = Vtbf + convShorts;
    float* ML    = (float*)(Opart + (size_t)B_ * T * (BR * D_));

    fa_prep<<<dim3(B_ * NQT), 256, 0, stream>>>(Q, K, V, Qbf, Kbf, Vtbf);
    fa_part<<<dim3(B_ * T), 256, 0, stream>>>(Qbf, Kbf, Vtbf, Opart, ML, CH, T);
    fa_combine<<<dim3((B_ * S_ * 16) / 256), 256, 0, stream>>>(Opart, ML, O, CH, T);
}